// Round 1
// baseline (671.080 us; speedup 1.0000x reference)
//
#include <hip/hip_runtime.h>
#include <hip/hip_bf16.h>

// ---------------------------------------------------------------------------
// AttentionLayer: conv3x3+BN+ReLU -> 1x1 q/k/v -> softmax(q^T k) -> V*attn^T
//                 -> gamma*out + x -> conv3x3+BN+ReLU
// B=2, C=64, Cqk=16, H=W=96, N=9216.
// Design notes (round 0):
//  - attention = flash-style, bf16 MFMA 16x16x32, swapped QK^T (S'=K*Q) so the
//    softmax j-reduction is per-lane regs + shfl_xor(16/32). P -> PV B-frag via
//    1.25KB per-wave LDS round trip. 1-wave blocks, 1152 blocks.
//  - convs are fp32 LDS-tiled (correctness-first; candidates for MFMA later).
// ---------------------------------------------------------------------------

using short8 = __attribute__((ext_vector_type(8))) short;   // 8 bf16 (4 VGPRs)
using f32x4  = __attribute__((ext_vector_type(4))) float;   // MFMA acc

#define NPIX 9216
#define HH 96
#define WW 96

// ---------------- conv3x3 + BN(eval) + ReLU (fp32) --------------------------
__global__ __launch_bounds__(256) void conv3x3_bn_relu(
    const float* __restrict__ in, const float* __restrict__ w,
    const float* __restrict__ gg, const float* __restrict__ bb_,
    const float* __restrict__ mm, const float* __restrict__ vv,
    float* __restrict__ out)
{
  __shared__ float wl[576];        // 64 ci * 9 taps for this co
  __shared__ float inl[18][18];    // 16x16 tile + halo
  const int tile = blockIdx.x;     // 0..35
  const int co   = blockIdx.y;     // 0..63
  const int b    = blockIdx.z;     // 0..1
  const int tx0 = (tile % 6) * 16, ty0 = (tile / 6) * 16;
  const int tid = threadIdx.x;
  const int tx = tid & 15, ty = tid >> 4;

  for (int idx = tid; idx < 576; idx += 256) wl[idx] = w[co * 576 + idx];
  const float sc = gg[co] * rsqrtf(vv[co] + 1e-5f);
  const float sh = bb_[co] - mm[co] * sc;

  const float* inb = in + (size_t)b * 64 * HH * WW;
  float acc = 0.f;
  for (int ci = 0; ci < 64; ++ci) {
    __syncthreads();
    for (int idx = tid; idx < 324; idx += 256) {
      const int r = idx / 18, c2 = idx - r * 18;
      const int gy = ty0 + r - 1, gx = tx0 + c2 - 1;
      float v = 0.f;
      if (gy >= 0 && gy < HH && gx >= 0 && gx < WW)
        v = inb[(size_t)ci * HH * WW + gy * WW + gx];
      inl[r][c2] = v;
    }
    __syncthreads();
    const float* wp = &wl[ci * 9];
#pragma unroll
    for (int kh = 0; kh < 3; ++kh)
#pragma unroll
      for (int kw = 0; kw < 3; ++kw)
        acc += inl[ty + kh][tx + kw] * wp[kh * 3 + kw];
  }
  const float val = fmaxf(sc * acc + sh, 0.f);
  out[((size_t)(b * 64 + co) * HH + ty0 + ty) * WW + tx0 + tx] = val;
}

// ---------------- 1x1 q/k/v convs -> bf16 tensors for MFMA ------------------
// qtp/ktp: [B][N][32] bf16, channel-transposed, c=16..31 zero-padded (MFMA K-pad)
// vb:      [B][64][N] bf16
__global__ __launch_bounds__(256) void qkv_kernel(
    const float* __restrict__ x1,
    const float* __restrict__ wq, const float* __restrict__ bq,
    const float* __restrict__ wk, const float* __restrict__ bk,
    const float* __restrict__ wv, const float* __restrict__ bv,
    __hip_bfloat16* __restrict__ qtp, __hip_bfloat16* __restrict__ ktp,
    __hip_bfloat16* __restrict__ vb)
{
  __shared__ float xl[64][128];
  const int bbk = blockIdx.x;       // 0..143
  const int b   = bbk / 72;
  const int n0  = (bbk % 72) * 128;
  const int tid = threadIdx.x;
  for (int idx = tid; idx < 64 * 128; idx += 256) {
    const int ci = idx >> 7, nn = idx & 127;
    xl[ci][nn] = x1[((size_t)(b * 64 + ci)) * NPIX + n0 + nn];
  }
  __syncthreads();
  const int nn = tid & 127;
  const int half = tid >> 7;
  const int n = n0 + nn;
  const __hip_bfloat16 z = __float2bfloat16(0.f);
  if (half == 0) {
    // q and k (16 channels each) for this pixel, plus zero pads
    for (int co = 0; co < 16; ++co) {
      float aq = bq[co], ak = bk[co];
#pragma unroll 8
      for (int ci = 0; ci < 64; ++ci) {
        const float xv = xl[ci][nn];
        aq += wq[co * 64 + ci] * xv;
        ak += wk[co * 64 + ci] * xv;
      }
      qtp[((size_t)(b * NPIX + n)) * 32 + co] = __float2bfloat16(aq);
      ktp[((size_t)(b * NPIX + n)) * 32 + co] = __float2bfloat16(ak);
    }
    for (int c = 16; c < 32; ++c) {
      qtp[((size_t)(b * NPIX + n)) * 32 + c] = z;
      ktp[((size_t)(b * NPIX + n)) * 32 + c] = z;
    }
  } else {
    for (int co = 0; co < 64; ++co) {
      float av = bv[co];
#pragma unroll 8
      for (int ci = 0; ci < 64; ++ci) av += wv[co * 64 + ci] * xl[ci][nn];
      vb[((size_t)(b * 64 + co)) * NPIX + n] = __float2bfloat16(av);
    }
  }
}

// ---------------- flash attention (bf16 MFMA) + gamma*out + x ---------------
// grid (N/16, B), block 64 (one wave). Lane: g=lane>>4, col=lane&15.
// S' = mfma(A=K-tile[16j x 32c], B=Q-tile[32c x 16i]) -> lane holds S'[4g+r, col]
// PV:  acc[ct] = mfma(A=V-tile[16c x 32j], B=P[32j x 16i], acc[ct])
__global__ __launch_bounds__(64) void attn_kernel(
    const __hip_bfloat16* __restrict__ qtp, const __hip_bfloat16* __restrict__ ktp,
    const __hip_bfloat16* __restrict__ vb, const float* __restrict__ x1,
    const float* __restrict__ gamma_p, float* __restrict__ of)
{
  const int b    = blockIdx.y;
  const int i0   = blockIdx.x * 16;
  const int lane = threadIdx.x;
  const int g    = lane >> 4;
  const int col  = lane & 15;

  __shared__ __align__(16) __hip_bfloat16 plds[16 * 40];   // P tile [i][j], stride 40

  // Q B-frag, held across the whole j sweep: B[c=8g+jj][i=col]
  const short8 qf = *reinterpret_cast<const short8*>(
      qtp + ((size_t)(b * NPIX + i0 + col)) * 32 + 8 * g);

  float m = -INFINITY, l = 0.f;
  f32x4 acc[4];
#pragma unroll
  for (int ct = 0; ct < 4; ++ct) acc[ct] = (f32x4){0.f, 0.f, 0.f, 0.f};

  const __hip_bfloat16* kbase = ktp + (size_t)b * NPIX * 32;
  const __hip_bfloat16* vbase = vb + (size_t)b * 64 * NPIX;

  for (int jt = 0; jt < NPIX / 32; ++jt) {
    const int j0 = jt * 32;
    // K A-frags: A[j'=col][c=8g+jj]  (rows j0+col and j0+16+col)
    const short8 kf0 = *reinterpret_cast<const short8*>(
        kbase + ((size_t)(j0 + col)) * 32 + 8 * g);
    const short8 kf1 = *reinterpret_cast<const short8*>(
        kbase + ((size_t)(j0 + 16 + col)) * 32 + 8 * g);
    const f32x4 zf = (f32x4){0.f, 0.f, 0.f, 0.f};
    f32x4 s0 = __builtin_amdgcn_mfma_f32_16x16x32_bf16(kf0, qf, zf, 0, 0, 0);
    f32x4 s1 = __builtin_amdgcn_mfma_f32_16x16x32_bf16(kf1, qf, zf, 0, 0, 0);
    // lane holds energy[i, j0+4g+r] (s0) and energy[i, j0+16+4g+r] (s1), i=i0+col

    // online softmax over the 32 j's of this step
    float pm = fmaxf(fmaxf(fmaxf(s0[0], s0[1]), fmaxf(s0[2], s0[3])),
                     fmaxf(fmaxf(s1[0], s1[1]), fmaxf(s1[2], s1[3])));
    pm = fmaxf(pm, __shfl_xor(pm, 16));
    pm = fmaxf(pm, __shfl_xor(pm, 32));
    const float mnew = fmaxf(m, pm);
    const float corr = __expf(m - mnew);   // exp(-inf)=0 on first tile
    float p[8];
#pragma unroll
    for (int r = 0; r < 4; ++r) p[r] = __expf(s0[r] - mnew);
#pragma unroll
    for (int r = 0; r < 4; ++r) p[4 + r] = __expf(s1[r] - mnew);
    float ps = ((p[0] + p[1]) + (p[2] + p[3])) + ((p[4] + p[5]) + (p[6] + p[7]));
    ps += __shfl_xor(ps, 16);
    ps += __shfl_xor(ps, 32);
    l = l * corr + ps;
    m = mnew;
#pragma unroll
    for (int ct = 0; ct < 4; ++ct) acc[ct] *= corr;

    // P -> LDS [i=col][j], bf16
    __hip_bfloat16* prow = plds + col * 40;
#pragma unroll
    for (int r = 0; r < 4; ++r) prow[4 * g + r]      = __float2bfloat16(p[r]);
#pragma unroll
    for (int r = 0; r < 4; ++r) prow[16 + 4 * g + r] = __float2bfloat16(p[4 + r]);
    __syncthreads();   // 1-wave block: lgkmcnt drain + cheap barrier
    // PV B-frag: B[j=8g+jj][i=col]
    const short8 pf = *reinterpret_cast<const short8*>(plds + col * 40 + 8 * g);
    __syncthreads();   // protect LDS from next iteration's writes

#pragma unroll
    for (int ct = 0; ct < 4; ++ct) {
      // V A-frag: A[c'=col][j=8g+jj], c = ct*16+col
      const short8 vf = *reinterpret_cast<const short8*>(
          vbase + ((size_t)(ct * 16 + col)) * NPIX + j0 + 8 * g);
      acc[ct] = __builtin_amdgcn_mfma_f32_16x16x32_bf16(vf, pf, acc[ct], 0, 0, 0);
    }
  }

  const float invl = 1.f / l;
  const float gm = gamma_p[0];
#pragma unroll
  for (int ct = 0; ct < 4; ++ct) {
#pragma unroll
    for (int r = 0; r < 4; ++r) {
      const int c = ct * 16 + 4 * g + r;          // C/D: row=4g+r, col=i
      const size_t idx = ((size_t)(b * 64 + c)) * NPIX + i0 + col;
      of[idx] = acc[ct][r] * invl * gm + x1[idx];
    }
  }
}

// ---------------------------------------------------------------------------
extern "C" void kernel_launch(void* const* d_in, const int* in_sizes, int n_in,
                              void* d_out, int out_size, void* d_ws, size_t ws_size,
                              hipStream_t stream) {
  const float* x      = (const float*)d_in[0];
  const float* w_pre  = (const float*)d_in[1];
  const float* bn1_g  = (const float*)d_in[2];
  const float* bn1_b  = (const float*)d_in[3];
  const float* bn1_m  = (const float*)d_in[4];
  const float* bn1_v  = (const float*)d_in[5];
  const float* wq     = (const float*)d_in[6];
  const float* bq     = (const float*)d_in[7];
  const float* wk     = (const float*)d_in[8];
  const float* bk     = (const float*)d_in[9];
  const float* wv     = (const float*)d_in[10];
  const float* bv     = (const float*)d_in[11];
  const float* w_fin  = (const float*)d_in[12];
  const float* bn2_g  = (const float*)d_in[13];
  const float* bn2_b  = (const float*)d_in[14];
  const float* bn2_m  = (const float*)d_in[15];
  const float* bn2_v  = (const float*)d_in[16];
  const float* gamma  = (const float*)d_in[17];
  float* out = (float*)d_out;

  // workspace layout
  char* ws = (char*)d_ws;
  float* x1 = (float*)(ws);                                   // 4,718,592 B
  float* of = (float*)(ws + 4718592);                          // 4,718,592 B
  __hip_bfloat16* qtp = (__hip_bfloat16*)(ws + 9437184);       // 1,179,648 B
  __hip_bfloat16* ktp = (__hip_bfloat16*)(ws + 10616832);      // 1,179,648 B
  __hip_bfloat16* vb  = (__hip_bfloat16*)(ws + 11796480);      // 2,359,296 B

  // 1) pre conv + BN + ReLU
  conv3x3_bn_relu<<<dim3(36, 64, 2), 256, 0, stream>>>(
      x, w_pre, bn1_g, bn1_b, bn1_m, bn1_v, x1);
  // 2) q/k/v 1x1 convs -> bf16 MFMA-ready tensors
  qkv_kernel<<<dim3(144), 256, 0, stream>>>(
      x1, wq, bq, wk, bk, wv, bv, qtp, ktp, vb);
  // 3) flash attention + gamma*out + residual
  attn_kernel<<<dim3(NPIX / 16, 2), 64, 0, stream>>>(
      qtp, ktp, vb, x1, gamma, of);
  // 4) final conv + BN + ReLU
  conv3x3_bn_relu<<<dim3(36, 64, 2), 256, 0, stream>>>(
      of, w_fin, bn2_g, bn2_b, bn2_m, bn2_v, out);
}

// Round 2
// 391.624 us; speedup vs baseline: 1.7136x; 1.7136x over previous
//
#include <hip/hip_runtime.h>
#include <hip/hip_bf16.h>

// ---------------------------------------------------------------------------
// AttentionLayer round 2:
//  - conv3x3: 8-co per block (barrier/staging amortized 8x)
//  - qkv: bf16 MFMA GEMM [96 x 64] x [64 x 18432], 1-wave blocks
//  - attn: flash, QBLK=32, KVBLK=64, 8 waves/block j-split + LDS-atomic merge,
//          exp2-domain softmax (LOG2E folded into q), per-wave P tile in LDS
//          with within-wave lgkmcnt ordering (no barriers in main loop).
// ---------------------------------------------------------------------------

using short8 = __attribute__((ext_vector_type(8))) short;   // 8 bf16
using f32x4  = __attribute__((ext_vector_type(4))) float;   // MFMA acc

#define NPIX 9216
#define HH 96
#define WW 96
#define LOG2E 1.44269504088896340736f
#define CHUNK 18   // jt64 steps per wave (144 total / 8 waves)

__device__ __forceinline__ unsigned short f2bf(float f) {
  unsigned int x = __builtin_bit_cast(unsigned int, f);
  return (unsigned short)((x + 0x7fffu + ((x >> 16) & 1u)) >> 16);
}

// ---------------- conv3x3 + BN(eval) + ReLU (fp32), 8 co per block ----------
__global__ __launch_bounds__(256) void conv3x3_bn_relu(
    const float* __restrict__ in, const float* __restrict__ w,
    const float* __restrict__ gg, const float* __restrict__ bb_,
    const float* __restrict__ mm, const float* __restrict__ vv,
    float* __restrict__ out)
{
  __shared__ float wl[8 * 64 * 9];   // [c][ci][tap]
  __shared__ float inl[18][18];
  const int tile = blockIdx.x;       // 0..35
  const int cg   = blockIdx.y;       // 0..7  -> co = cg*8 + c
  const int b    = blockIdx.z;
  const int tx0 = (tile % 6) * 16, ty0 = (tile / 6) * 16;
  const int tid = threadIdx.x;
  const int tx = tid & 15, ty = tid >> 4;

  for (int idx = tid; idx < 8 * 64 * 9; idx += 256)
    wl[idx] = w[(cg * 8) * 576 + idx];

  const float* inb = in + (size_t)b * 64 * HH * WW;
  float acc[8];
#pragma unroll
  for (int c = 0; c < 8; ++c) acc[c] = 0.f;

  for (int ci = 0; ci < 64; ++ci) {
    __syncthreads();
    for (int idx = tid; idx < 324; idx += 256) {
      const int r = idx / 18, c2 = idx - r * 18;
      const int gy = ty0 + r - 1, gx = tx0 + c2 - 1;
      float v = 0.f;
      if (gy >= 0 && gy < HH && gx >= 0 && gx < WW)
        v = inb[(size_t)ci * HH * WW + gy * WW + gx];
      inl[r][c2] = v;
    }
    __syncthreads();
    float r9[9];
#pragma unroll
    for (int kh = 0; kh < 3; ++kh)
#pragma unroll
      for (int kw = 0; kw < 3; ++kw) r9[kh * 3 + kw] = inl[ty + kh][tx + kw];
#pragma unroll
    for (int c = 0; c < 8; ++c) {
      const float* wp = &wl[(c * 64 + ci) * 9];
#pragma unroll
      for (int t = 0; t < 9; ++t) acc[c] += r9[t] * wp[t];
    }
  }
#pragma unroll
  for (int c = 0; c < 8; ++c) {
    const int co = cg * 8 + c;
    const float sc = gg[co] * rsqrtf(vv[co] + 1e-5f);
    const float sh = bb_[co] - mm[co] * sc;
    out[((size_t)(b * 64 + co) * HH + ty0 + ty) * WW + tx0 + tx] =
        fmaxf(sc * acc[c] + sh, 0.f);
  }
}

// ---------------- 1x1 q/k/v as bf16 MFMA GEMM -------------------------------
// grid (576 pix-tiles, 6 co-tiles, 2 b), block 64 (1 wave).
// co-tile 0 = q (x LOG2E), 1 = k, 2..5 = v rows (cotile-2)*16..
__global__ __launch_bounds__(64) void qkv_kernel(
    const float* __restrict__ x1,
    const float* __restrict__ wq, const float* __restrict__ bq,
    const float* __restrict__ wk, const float* __restrict__ bk,
    const float* __restrict__ wv, const float* __restrict__ bv,
    __hip_bfloat16* __restrict__ qtp, __hip_bfloat16* __restrict__ ktp,
    __hip_bfloat16* __restrict__ vb)
{
  const int pix0 = blockIdx.x * 16;
  const int cot  = blockIdx.y;
  const int b    = blockIdx.z;
  const int lane = threadIdx.x;
  const int g    = lane >> 4;
  const int col  = lane & 15;

  const float* wr;
  const float* bias;
  if (cot == 0)      { wr = wq + col * 64; bias = bq; }
  else if (cot == 1) { wr = wk + col * 64; bias = bk; }
  else               { wr = wv + ((cot - 2) * 16 + col) * 64; bias = bv + (cot - 2) * 16; }

  f32x4 acc = (f32x4){0.f, 0.f, 0.f, 0.f};
  const float* xb = x1 + (size_t)b * 64 * NPIX;
#pragma unroll
  for (int kt = 0; kt < 2; ++kt) {
    // A-frag: W[row=col][k=kt*32+8g+jj]
    const float4 wa = *(const float4*)(wr + kt * 32 + 8 * g);
    const float4 wb2 = *(const float4*)(wr + kt * 32 + 8 * g + 4);
    short8 af;
    af[0] = (short)f2bf(wa.x); af[1] = (short)f2bf(wa.y);
    af[2] = (short)f2bf(wa.z); af[3] = (short)f2bf(wa.w);
    af[4] = (short)f2bf(wb2.x); af[5] = (short)f2bf(wb2.y);
    af[6] = (short)f2bf(wb2.z); af[7] = (short)f2bf(wb2.w);
    // B-frag: X[k=kt*32+8g+jj][pix0+col]
    short8 bf;
#pragma unroll
    for (int jj = 0; jj < 8; ++jj)
      bf[jj] = (short)f2bf(xb[(size_t)(kt * 32 + 8 * g + jj) * NPIX + pix0 + col]);
    acc = __builtin_amdgcn_mfma_f32_16x16x32_bf16(af, bf, acc, 0, 0, 0);
  }
  const float scl = (cot == 0) ? LOG2E : 1.f;
  if (cot < 2) {
    unsigned short* dst = (unsigned short*)(cot == 0 ? qtp : ktp);
    dst += ((size_t)(b * NPIX + pix0 + col)) * 32;
#pragma unroll
    for (int r = 0; r < 4; ++r) {
      const int cl = 4 * g + r;
      dst[cl] = f2bf((acc[r] + bias[cl]) * scl);
      dst[16 + cl] = 0;   // zero-pad channels 16..31
    }
  } else {
    unsigned short* dst = (unsigned short*)vb;
#pragma unroll
    for (int r = 0; r < 4; ++r) {
      const int cl = 4 * g + r;
      dst[((size_t)(b * 64 + (cot - 2) * 16 + cl)) * NPIX + pix0 + col] =
          f2bf(acc[r] + bias[cl]);
    }
  }
}

// ---------------- flash attention, 8-wave j-split ---------------------------
// grid (288, 2), block 512. Wave w handles jt64 in [w*18, w*18+18).
__global__ __launch_bounds__(512, 4) void attn_kernel(
    const __hip_bfloat16* __restrict__ qtp, const __hip_bfloat16* __restrict__ ktp,
    const __hip_bfloat16* __restrict__ vb, const float* __restrict__ x1,
    const float* __restrict__ gamma_p, float* __restrict__ of)
{
  __shared__ unsigned short plds[8][32][88];  // per-wave P tiles (176B rows)
  __shared__ float obuf[32][65];              // merged numerator [il][c]
  __shared__ float2 mlb[8][2][16];            // per-wave (m,l)
  __shared__ float lbuf[32];

  const int b    = blockIdx.y;
  const int i0   = blockIdx.x * 32;
  const int tid  = threadIdx.x;
  const int w    = tid >> 6;
  const int lane = tid & 63;
  const int g    = lane >> 4;
  const int col  = lane & 15;

  for (int idx = tid; idx < 32 * 65; idx += 512) ((float*)obuf)[idx] = 0.f;
  if (tid < 32) lbuf[tid] = 0.f;
  __syncthreads();

  const __hip_bfloat16* kb    = ktp + (size_t)b * NPIX * 32;
  const __hip_bfloat16* vbase = vb + (size_t)b * 64 * NPIX;

  short8 qf[2];
#pragma unroll
  for (int qh = 0; qh < 2; ++qh)
    qf[qh] = *(const short8*)(qtp + ((size_t)b * NPIX + i0 + qh * 16 + col) * 32 + 8 * g);

  float m[2] = {-INFINITY, -INFINITY};
  float l[2] = {0.f, 0.f};
  f32x4 acc[2][4];
#pragma unroll
  for (int qh = 0; qh < 2; ++qh)
#pragma unroll
    for (int ct = 0; ct < 4; ++ct) acc[qh][ct] = (f32x4){0.f, 0.f, 0.f, 0.f};

  for (int t = 0; t < CHUNK; ++t) {
    const int j0 = (w * CHUNK + t) * 64;
    const f32x4 zf = (f32x4){0.f, 0.f, 0.f, 0.f};
    f32x4 sv[2][4];
    __builtin_amdgcn_s_setprio(1);
#pragma unroll
    for (int s = 0; s < 4; ++s) {
      const short8 kf = *(const short8*)(kb + (size_t)(j0 + 16 * s + col) * 32 + 8 * g);
      sv[0][s] = __builtin_amdgcn_mfma_f32_16x16x32_bf16(kf, qf[0], zf, 0, 0, 0);
      sv[1][s] = __builtin_amdgcn_mfma_f32_16x16x32_bf16(kf, qf[1], zf, 0, 0, 0);
    }
    __builtin_amdgcn_s_setprio(0);
    // online softmax (exp2 domain), per query-half
#pragma unroll
    for (int qh = 0; qh < 2; ++qh) {
      float pm = -INFINITY;
#pragma unroll
      for (int s = 0; s < 4; ++s)
#pragma unroll
        for (int r = 0; r < 4; ++r) pm = fmaxf(pm, sv[qh][s][r]);
      pm = fmaxf(pm, __shfl_xor(pm, 16));
      pm = fmaxf(pm, __shfl_xor(pm, 32));
      const float mnew = fmaxf(m[qh], pm);
      const float corr = exp2f(m[qh] - mnew);
      float ps = 0.f;
#pragma unroll
      for (int s = 0; s < 4; ++s) {
        float e0 = exp2f(sv[qh][s][0] - mnew);
        float e1 = exp2f(sv[qh][s][1] - mnew);
        float e2 = exp2f(sv[qh][s][2] - mnew);
        float e3 = exp2f(sv[qh][s][3] - mnew);
        sv[qh][s][0] = e0; sv[qh][s][1] = e1; sv[qh][s][2] = e2; sv[qh][s][3] = e3;
        ps += (e0 + e1) + (e2 + e3);
      }
      ps += __shfl_xor(ps, 16);
      ps += __shfl_xor(ps, 32);
      l[qh] = l[qh] * corr + ps;
      m[qh] = mnew;
#pragma unroll
      for (int ct = 0; ct < 4; ++ct) acc[qh][ct] *= corr;
      // P -> per-wave LDS tile, row = qh*16+col, local j = 16s+4g+r
      const int row = qh * 16 + col;
#pragma unroll
      for (int s = 0; s < 4; ++s) {
        unsigned int lo = (unsigned)f2bf(sv[qh][s][0]) | ((unsigned)f2bf(sv[qh][s][1]) << 16);
        unsigned int hi = (unsigned)f2bf(sv[qh][s][2]) | ((unsigned)f2bf(sv[qh][s][3]) << 16);
        uint2 u; u.x = lo; u.y = hi;
        *(uint2*)&plds[w][row][16 * s + 4 * g] = u;
      }
    }
    // within-wave ordering: drain ds_writes before ds_reads (no barrier needed,
    // plds slice is wave-private). sched_barrier per guide rule #18.
    asm volatile("s_waitcnt lgkmcnt(0)" ::: "memory");
    __builtin_amdgcn_sched_barrier(0);
#pragma unroll
    for (int h = 0; h < 2; ++h) {
      const short8 pf0 = *(const short8*)&plds[w][col][32 * h + 8 * g];
      const short8 pf1 = *(const short8*)&plds[w][16 + col][32 * h + 8 * g];
      __builtin_amdgcn_s_setprio(1);
#pragma unroll
      for (int ct = 0; ct < 4; ++ct) {
        const short8 vf = *(const short8*)(vbase + (size_t)(ct * 16 + col) * NPIX + j0 + 32 * h + 8 * g);
        acc[0][ct] = __builtin_amdgcn_mfma_f32_16x16x32_bf16(vf, pf0, acc[0][ct], 0, 0, 0);
        acc[1][ct] = __builtin_amdgcn_mfma_f32_16x16x32_bf16(vf, pf1, acc[1][ct], 0, 0, 0);
      }
      __builtin_amdgcn_s_setprio(0);
    }
  }

  // ---- merge 8 waves ----
  if (g == 0) {
#pragma unroll
    for (int qh = 0; qh < 2; ++qh) {
      float2 t2; t2.x = m[qh]; t2.y = l[qh];
      mlb[w][qh][col] = t2;
    }
  }
  __syncthreads();
  float f[2];
#pragma unroll
  for (int qh = 0; qh < 2; ++qh) {
    float M = -INFINITY;
#pragma unroll
    for (int ww = 0; ww < 8; ++ww) M = fmaxf(M, mlb[ww][qh][col].x);
    f[qh] = exp2f(m[qh] - M);
  }
  if (g == 0) {
#pragma unroll
    for (int qh = 0; qh < 2; ++qh) atomicAdd(&lbuf[qh * 16 + col], l[qh] * f[qh]);
  }
#pragma unroll
  for (int qh = 0; qh < 2; ++qh)
#pragma unroll
    for (int ct = 0; ct < 4; ++ct)
#pragma unroll
      for (int r = 0; r < 4; ++r)
        atomicAdd(&obuf[qh * 16 + col][ct * 16 + 4 * g + r], acc[qh][ct][r] * f[qh]);
  __syncthreads();

  const float gm = gamma_p[0];
  for (int idx = tid; idx < 2048; idx += 512) {
    const int il = idx & 31, c = idx >> 5;
    const size_t o = ((size_t)(b * 64 + c)) * NPIX + i0 + il;
    of[o] = obuf[il][c] / lbuf[il] * gm + x1[o];
  }
}

// ---------------------------------------------------------------------------
extern "C" void kernel_launch(void* const* d_in, const int* in_sizes, int n_in,
                              void* d_out, int out_size, void* d_ws, size_t ws_size,
                              hipStream_t stream) {
  const float* x      = (const float*)d_in[0];
  const float* w_pre  = (const float*)d_in[1];
  const float* bn1_g  = (const float*)d_in[2];
  const float* bn1_b  = (const float*)d_in[3];
  const float* bn1_m  = (const float*)d_in[4];
  const float* bn1_v  = (const float*)d_in[5];
  const float* wq     = (const float*)d_in[6];
  const float* bq     = (const float*)d_in[7];
  const float* wk     = (const float*)d_in[8];
  const float* bk     = (const float*)d_in[9];
  const float* wv     = (const float*)d_in[10];
  const float* bv     = (const float*)d_in[11];
  const float* w_fin  = (const float*)d_in[12];
  const float* bn2_g  = (const float*)d_in[13];
  const float* bn2_b  = (const float*)d_in[14];
  const float* bn2_m  = (const float*)d_in[15];
  const float* bn2_v  = (const float*)d_in[16];
  const float* gamma  = (const float*)d_in[17];
  float* out = (float*)d_out;

  char* ws = (char*)d_ws;
  float* x1 = (float*)(ws);                                    // 4,718,592 B
  float* of = (float*)(ws + 4718592);                          // 4,718,592 B
  __hip_bfloat16* qtp = (__hip_bfloat16*)(ws + 9437184);       // 1,179,648 B
  __hip_bfloat16* ktp = (__hip_bfloat16*)(ws + 10616832);      // 1,179,648 B
  __hip_bfloat16* vb  = (__hip_bfloat16*)(ws + 11796480);      // 2,359,296 B

  conv3x3_bn_relu<<<dim3(36, 8, 2), 256, 0, stream>>>(
      x, w_pre, bn1_g, bn1_b, bn1_m, bn1_v, x1);
  qkv_kernel<<<dim3(576, 6, 2), 64, 0, stream>>>(
      x1, wq, bq, wk, bk, wv, bv, qtp, ktp, vb);
  attn_kernel<<<dim3(NPIX / 32, 2), 512, 0, stream>>>(
      qtp, ktp, vb, x1, gamma, of);
  conv3x3_bn_relu<<<dim3(36, 8, 2), 256, 0, stream>>>(
      of, w_fin, bn2_g, bn2_b, bn2_m, bn2_v, out);
}

// Round 3
// 348.478 us; speedup vs baseline: 1.9257x; 1.1238x over previous
//
#include <hip/hip_runtime.h>
#include <hip/hip_bf16.h>

// ---------------------------------------------------------------------------
// AttentionLayer round 2:
//  - padded (98x98) fp32 planes for both convs: no bounds checks, 4-ci chunks
//  - qkv: bf16 MFMA GEMM, outputs q/k as [N][16] rows (LOG2E folded into q)
//  - attn: 32x32x16 MFMA (K=16 exact), in-register softmax via
//    v_cvt_pk_bf16_f32 + v_permlane32_swap_b32 (no LDS P tile), defer-max,
//    raw v_exp_f32, manual K/V prefetch, 8-wave j-split + LDS merge.
// ---------------------------------------------------------------------------

using short8 = __attribute__((ext_vector_type(8))) short;   // 8 bf16
using f32x4  = __attribute__((ext_vector_type(4))) float;
using f32x16 = __attribute__((ext_vector_type(16))) float;
using u32x4  = __attribute__((ext_vector_type(4))) unsigned;
typedef unsigned u32;
typedef unsigned short ushort;

#define NPIX 9216
#define HH 96
#define WW 96
#define PW 98
#define PLANE 9604            // 98*98
#define LOG2E 1.44269504088896340736f

__device__ __forceinline__ unsigned short f2bf(float f) {
  unsigned int x = __builtin_bit_cast(unsigned int, f);
  return (unsigned short)((x + 0x7fffu + ((x >> 16) & 1u)) >> 16);
}

// ---------------- pad copy: x[96x96] -> xp[98x98] interior ------------------
__global__ __launch_bounds__(256) void pad_copy(
    const float* __restrict__ in, float* __restrict__ outp)
{
  const int plane = blockIdx.x;   // 0..127 (b*64+c)
  const float* src = in + (size_t)plane * 9216;
  float* dst = outp + (size_t)plane * PLANE;
  for (int idx = threadIdx.x; idx < 9216; idx += 256) {
    const int y = idx / 96, x = idx - y * 96;
    dst[(y + 1) * PW + x + 1] = src[idx];
  }
}

// ---------------- conv3x3 + BN + ReLU, padded input, 8 co / block -----------
template <bool PADOUT>
__global__ __launch_bounds__(256) void conv3x3_bn_relu(
    const float* __restrict__ in, const float* __restrict__ w,
    const float* __restrict__ gg, const float* __restrict__ bb_,
    const float* __restrict__ mm, const float* __restrict__ vv,
    float* __restrict__ out)
{
  __shared__ float wl[4608];          // 8 co x 64 ci x 9
  __shared__ float inl[4][18][18];    // 4 ci planes, 16x16 tile + halo
  const int tile = blockIdx.x;        // 0..35
  const int cg   = blockIdx.y;        // 0..7
  const int b    = blockIdx.z;
  const int tx0 = (tile % 6) * 16, ty0 = (tile / 6) * 16;
  const int tid = threadIdx.x;
  const int tx = tid & 15, ty = tid >> 4;

  for (int idx = tid; idx < 4608; idx += 256) wl[idx] = w[cg * 8 * 576 + idx];

  const float* inb = in + (size_t)b * 64 * PLANE;
  float acc[8];
#pragma unroll
  for (int c = 0; c < 8; ++c) acc[c] = 0.f;

  for (int c0 = 0; c0 < 64; c0 += 4) {
    __syncthreads();
    for (int idx = tid; idx < 1296; idx += 256) {
      const int cc = idx / 324, rem = idx - cc * 324;
      const int r = rem / 18, cx = rem - r * 18;
      inl[cc][r][cx] = inb[(size_t)(c0 + cc) * PLANE + (ty0 + r) * PW + tx0 + cx];
    }
    __syncthreads();
#pragma unroll
    for (int cc = 0; cc < 4; ++cc) {
      float r9[9];
#pragma unroll
      for (int kh = 0; kh < 3; ++kh)
#pragma unroll
        for (int kw = 0; kw < 3; ++kw) r9[kh * 3 + kw] = inl[cc][ty + kh][tx + kw];
#pragma unroll
      for (int c = 0; c < 8; ++c) {
        const float* wp = &wl[(c * 64 + c0 + cc) * 9];
#pragma unroll
        for (int t = 0; t < 9; ++t) acc[c] += r9[t] * wp[t];
      }
    }
  }
#pragma unroll
  for (int c = 0; c < 8; ++c) {
    const int co = cg * 8 + c;
    const float sc = gg[co] * rsqrtf(vv[co] + 1e-5f);
    const float sh = bb_[co] - mm[co] * sc;
    const float val = fmaxf(sc * acc[c] + sh, 0.f);
    if (PADOUT)
      out[(size_t)(b * 64 + co) * PLANE + (ty0 + ty + 1) * PW + tx0 + tx + 1] = val;
    else
      out[((size_t)(b * 64 + co) * 96 + ty0 + ty) * 96 + tx0 + tx] = val;
  }
}

// ---------------- 1x1 q/k/v as bf16 MFMA GEMM -------------------------------
// grid (576 pix-tiles, 6 co-tiles, 2 b), block 64.
// cot 0 = q (scaled by LOG2E) -> qtp[N][16]; 1 = k -> ktp[N][16];
// 2..5 = v channel-quarters -> vb[64][N].
__global__ __launch_bounds__(64) void qkv_kernel(
    const float* __restrict__ x1p,
    const float* __restrict__ wq, const float* __restrict__ bq,
    const float* __restrict__ wk, const float* __restrict__ bk,
    const float* __restrict__ wv, const float* __restrict__ bv,
    __hip_bfloat16* __restrict__ qtp, __hip_bfloat16* __restrict__ ktp,
    __hip_bfloat16* __restrict__ vb)
{
  const int pix0 = blockIdx.x * 16;
  const int cot  = blockIdx.y;
  const int b    = blockIdx.z;
  const int lane = threadIdx.x;
  const int g    = lane >> 4;
  const int col  = lane & 15;

  const float* wr;
  const float* bias;
  if (cot == 0)      { wr = wq + col * 64; bias = bq; }
  else if (cot == 1) { wr = wk + col * 64; bias = bk; }
  else               { wr = wv + ((cot - 2) * 16 + col) * 64; bias = bv + (cot - 2) * 16; }

  const int yy = pix0 / 96, xx = pix0 - yy * 96;
  const int ro = (yy + 1) * PW + xx + 1;

  f32x4 acc = (f32x4){0.f, 0.f, 0.f, 0.f};
  const float* xb = x1p + (size_t)b * 64 * PLANE;
#pragma unroll
  for (int kt = 0; kt < 2; ++kt) {
    const float4 wa = *(const float4*)(wr + kt * 32 + 8 * g);
    const float4 wb2 = *(const float4*)(wr + kt * 32 + 8 * g + 4);
    short8 af;
    af[0] = (short)f2bf(wa.x); af[1] = (short)f2bf(wa.y);
    af[2] = (short)f2bf(wa.z); af[3] = (short)f2bf(wa.w);
    af[4] = (short)f2bf(wb2.x); af[5] = (short)f2bf(wb2.y);
    af[6] = (short)f2bf(wb2.z); af[7] = (short)f2bf(wb2.w);
    short8 bf;
#pragma unroll
    for (int jj = 0; jj < 8; ++jj)
      bf[jj] = (short)f2bf(xb[(size_t)(kt * 32 + 8 * g + jj) * PLANE + ro + col]);
    acc = __builtin_amdgcn_mfma_f32_16x16x32_bf16(af, bf, acc, 0, 0, 0);
  }
  if (cot < 2) {
    unsigned short* dst = (unsigned short*)(cot == 0 ? qtp : ktp);
    dst += ((size_t)(b * NPIX + pix0 + col)) * 16;
    const float scl = (cot == 0) ? LOG2E : 1.f;
#pragma unroll
    for (int r = 0; r < 4; ++r) {
      const int cl = 4 * g + r;
      dst[cl] = f2bf((acc[r] + bias[cl]) * scl);
    }
  } else {
    unsigned short* dst = (unsigned short*)vb;
#pragma unroll
    for (int r = 0; r < 4; ++r) {
      const int cl = 4 * g + r;
      dst[((size_t)(b * 64 + (cot - 2) * 16 + cl)) * NPIX + pix0 + col] =
          f2bf(acc[r] + bias[cl]);
    }
  }
}

// ---------------- flash attention, 32x32x16, in-register softmax ------------
// grid (288, 2), block 512 (8 waves). Wave w: j in [w*1152, (w+1)*1152).
// Lane: li = lane&31 (= query column i), hi = lane>>5.
// S' = mfma32(K[32j x 16c], Q[16c x 32i]): lane holds S[(r&3)+8*(r>>2)+4*hi][li].
__global__ __launch_bounds__(512, 4) void attn_kernel(
    const __hip_bfloat16* __restrict__ qtp, const __hip_bfloat16* __restrict__ ktp,
    const __hip_bfloat16* __restrict__ vbp, const float* __restrict__ x1p,
    const float* __restrict__ gamma_p, float* __restrict__ ofp)
{
  __shared__ float2 mlb[8][32];
  __shared__ float obuf[32][65];
  __shared__ float lbuf[32];

  const int b   = blockIdx.y;
  const int i0  = blockIdx.x * 32;
  const int tid = threadIdx.x;
  const int w   = tid >> 6;
  const int lane = tid & 63;
  const int li  = lane & 31;
  const int hi  = lane >> 5;

  for (int idx = tid; idx < 32 * 65; idx += 512) ((float*)obuf)[idx] = 0.f;
  if (tid < 32) lbuf[tid] = 0.f;
  __syncthreads();

  const ushort* kb  = (const ushort*)ktp + (size_t)b * NPIX * 16;
  const ushort* vbb = (const ushort*)vbp + (size_t)b * 64 * NPIX;

  const short8 qf = *(const short8*)((const ushort*)qtp +
      ((size_t)b * NPIX + i0 + li) * 16 + 8 * hi);

  float m = -INFINITY, l = 0.f;
  f32x16 acc0 = {}, acc1 = {};

  const int j0base = w * (NPIX / 8);
  const ushort* kptr = kb + (size_t)(j0base + li) * 16 + 8 * hi;
  const ushort* vp0 = vbb + (size_t)li * NPIX + j0base + 8 * hi;
  const ushort* vp1 = vbb + (size_t)(32 + li) * NPIX + j0base + 8 * hi;

  short8 kf  = *(const short8*)kptr;
  short8 va0 = *(const short8*)(vp0);
  short8 va1 = *(const short8*)(vp0 + 16);
  short8 vb0 = *(const short8*)(vp1);
  short8 vb1 = *(const short8*)(vp1 + 16);

  const f32x16 zf = {};
  for (int t = 0; t < 36; ++t) {
    f32x16 s = __builtin_amdgcn_mfma_f32_32x32x16_bf16(kf, qf, zf, 0, 0, 0);

    short8 kf_n, va0n, va1n, vb0n, vb1n;
    if (t < 35) {                 // prefetch next tile (uniform branch)
      kptr += 512; vp0 += 32; vp1 += 32;
      kf_n  = *(const short8*)kptr;
      va0n = *(const short8*)(vp0);
      va1n = *(const short8*)(vp0 + 16);
      vb0n = *(const short8*)(vp1);
      vb1n = *(const short8*)(vp1 + 16);
    }

    // row max over this tile (16 regs + partner half)
    float pm = fmaxf(fmaxf(fmaxf(s[0], s[1]), fmaxf(s[2], s[3])),
                     fmaxf(fmaxf(s[4], s[5]), fmaxf(s[6], s[7])));
    pm = fmaxf(pm, fmaxf(fmaxf(fmaxf(s[8], s[9]), fmaxf(s[10], s[11])),
                         fmaxf(fmaxf(s[12], s[13]), fmaxf(s[14], s[15]))));
    pm = fmaxf(pm, __shfl_xor(pm, 32));

    if (__any(pm > m + 8.f)) {    // defer-max rescale (T13)
      const float mnew = fmaxf(m, pm);
      const float corr = __builtin_amdgcn_exp2f(m - mnew);
      l *= corr;
      acc0 *= corr; acc1 *= corr;
      m = mnew;
    }

#pragma unroll
    for (int r = 0; r < 16; ++r) s[r] = __builtin_amdgcn_exp2f(s[r] - m);
    float ps = (((s[0] + s[1]) + (s[2] + s[3])) + ((s[4] + s[5]) + (s[6] + s[7]))) +
               (((s[8] + s[9]) + (s[10] + s[11])) + ((s[12] + s[13]) + (s[14] + s[15])));
    ps += __shfl_xor(ps, 32);
    l += ps;

    // pack P to bf16 pairs, redistribute across hi halves (T12)
    u32 c01, c23, c45, c67, d01, d23, d45, d67;
    asm("v_cvt_pk_bf16_f32 %0, %1, %2" : "=v"(c01) : "v"(s[0]),  "v"(s[1]));
    asm("v_cvt_pk_bf16_f32 %0, %1, %2" : "=v"(c23) : "v"(s[2]),  "v"(s[3]));
    asm("v_cvt_pk_bf16_f32 %0, %1, %2" : "=v"(c45) : "v"(s[4]),  "v"(s[5]));
    asm("v_cvt_pk_bf16_f32 %0, %1, %2" : "=v"(c67) : "v"(s[6]),  "v"(s[7]));
    asm("v_cvt_pk_bf16_f32 %0, %1, %2" : "=v"(d01) : "v"(s[8]),  "v"(s[9]));
    asm("v_cvt_pk_bf16_f32 %0, %1, %2" : "=v"(d23) : "v"(s[10]), "v"(s[11]));
    asm("v_cvt_pk_bf16_f32 %0, %1, %2" : "=v"(d45) : "v"(s[12]), "v"(s[13]));
    asm("v_cvt_pk_bf16_f32 %0, %1, %2" : "=v"(d67) : "v"(s[14]), "v"(s[15]));
    asm("v_permlane32_swap_b32 %0, %1" : "+v"(c45), "+v"(c01));
    asm("v_permlane32_swap_b32 %0, %1" : "+v"(c67), "+v"(c23));
    asm("v_permlane32_swap_b32 %0, %1" : "+v"(d45), "+v"(d01));
    asm("v_permlane32_swap_b32 %0, %1" : "+v"(d67), "+v"(d23));
    const short8 pf1 = __builtin_bit_cast(short8, (u32x4){c01, c23, c45, c67});
    const short8 pf2 = __builtin_bit_cast(short8, (u32x4){d01, d23, d45, d67});

    acc0 = __builtin_amdgcn_mfma_f32_32x32x16_bf16(va0, pf1, acc0, 0, 0, 0);
    acc0 = __builtin_amdgcn_mfma_f32_32x32x16_bf16(va1, pf2, acc0, 0, 0, 0);
    acc1 = __builtin_amdgcn_mfma_f32_32x32x16_bf16(vb0, pf1, acc1, 0, 0, 0);
    acc1 = __builtin_amdgcn_mfma_f32_32x32x16_bf16(vb1, pf2, acc1, 0, 0, 0);

    if (t < 35) { kf = kf_n; va0 = va0n; va1 = va1n; vb0 = vb0n; vb1 = vb1n; }
  }

  // ---- merge 8 waves ----
  if (hi == 0) { float2 t2; t2.x = m; t2.y = l; mlb[w][li] = t2; }
  __syncthreads();
  float M = -INFINITY;
#pragma unroll
  for (int ww = 0; ww < 8; ++ww) M = fmaxf(M, mlb[ww][li].x);
  const float f = __builtin_amdgcn_exp2f(m - M);
  if (hi == 0) atomicAdd(&lbuf[li], l * f);
#pragma unroll
  for (int r = 0; r < 16; ++r) {
    const int c = (r & 3) + 8 * (r >> 2) + 4 * hi;
    atomicAdd(&obuf[li][c], acc0[r] * f);
    atomicAdd(&obuf[li][c + 32], acc1[r] * f);
  }
  __syncthreads();

  const float gm = gamma_p[0];
  const int yy = i0 / 96, xx = i0 - yy * 96;
  const int ro = (yy + 1) * PW + xx + 1;
  for (int idx = tid; idx < 2048; idx += 512) {
    const int il = idx & 31, c = idx >> 5;
    const size_t o = (size_t)(b * 64 + c) * PLANE + ro + il;
    ofp[o] = obuf[il][c] / lbuf[il] * gm + x1p[o];
  }
}

// ---------------------------------------------------------------------------
extern "C" void kernel_launch(void* const* d_in, const int* in_sizes, int n_in,
                              void* d_out, int out_size, void* d_ws, size_t ws_size,
                              hipStream_t stream) {
  const float* x      = (const float*)d_in[0];
  const float* w_pre  = (const float*)d_in[1];
  const float* bn1_g  = (const float*)d_in[2];
  const float* bn1_b  = (const float*)d_in[3];
  const float* bn1_m  = (const float*)d_in[4];
  const float* bn1_v  = (const float*)d_in[5];
  const float* wq     = (const float*)d_in[6];
  const float* bq     = (const float*)d_in[7];
  const float* wk     = (const float*)d_in[8];
  const float* bk     = (const float*)d_in[9];
  const float* wv     = (const float*)d_in[10];
  const float* bv     = (const float*)d_in[11];
  const float* w_fin  = (const float*)d_in[12];
  const float* bn2_g  = (const float*)d_in[13];
  const float* bn2_b  = (const float*)d_in[14];
  const float* bn2_m  = (const float*)d_in[15];
  const float* bn2_v  = (const float*)d_in[16];
  const float* gamma  = (const float*)d_in[17];
  float* out = (float*)d_out;

  char* ws = (char*)d_ws;
  float* xp  = (float*)(ws);                                   // 4,917,248 B (reused as ofp)
  float* x1p = (float*)(ws + 4917248);                         // 4,917,248 B
  __hip_bfloat16* qtp = (__hip_bfloat16*)(ws + 9834496);       //   589,824 B
  __hip_bfloat16* ktp = (__hip_bfloat16*)(ws + 10424320);      //   589,824 B
  __hip_bfloat16* vb  = (__hip_bfloat16*)(ws + 11014144);      // 2,359,296 B
  float* ofp = xp;   // xp is dead after conv1; reuse (pad ring stays zero)

  // zero the padded planes (rings must be 0; interiors rewritten every launch)
  hipMemsetAsync(ws, 0, 9834496, stream);

  pad_copy<<<dim3(128), 256, 0, stream>>>(x, xp);
  conv3x3_bn_relu<true><<<dim3(36, 8, 2), 256, 0, stream>>>(
      xp, w_pre, bn1_g, bn1_b, bn1_m, bn1_v, x1p);
  qkv_kernel<<<dim3(576, 6, 2), 64, 0, stream>>>(
      x1p, wq, bq, wk, bk, wv, bv, qtp, ktp, vb);
  attn_kernel<<<dim3(288, 2), 512, 0, stream>>>(
      qtp, ktp, vb, x1p, gamma, ofp);
  conv3x3_bn_relu<false><<<dim3(36, 8, 2), 256, 0, stream>>>(
      ofp, w_fin, bn2_g, bn2_b, bn2_m, bn2_v, out);
}

// Round 4
// 335.686 us; speedup vs baseline: 1.9991x; 1.0381x over previous
//
#include <hip/hip_runtime.h>
#include <hip/hip_bf16.h>

// ---------------------------------------------------------------------------
// AttentionLayer round 3:
//  - V stored fragment-linear (vfrag[t][h][ks][lane][8]) -> attn V loads are
//    contiguous 1KB b128 per wave-instr (16 lines) instead of 64-line gathers
//  - softmax reductions via v_permlane32_swap_b32 (no LDS in the chain)
//  - conv3x3: weights via uniform scalar loads (s_load), input-only LDS,
//    8-ci chunks
// ---------------------------------------------------------------------------

using short8 = __attribute__((ext_vector_type(8))) short;   // 8 bf16
using f32x4  = __attribute__((ext_vector_type(4))) float;
using f32x16 = __attribute__((ext_vector_type(16))) float;
using u32x4  = __attribute__((ext_vector_type(4))) unsigned;
typedef unsigned u32;
typedef unsigned short ushort;

#define NPIX 9216
#define HH 96
#define WW 96
#define PW 98
#define PLANE 9604            // 98*98
#define LOG2E 1.44269504088896340736f

__device__ __forceinline__ unsigned short f2bf(float f) {
  unsigned int x = __builtin_bit_cast(unsigned int, f);
  return (unsigned short)((x + 0x7fffu + ((x >> 16) & 1u)) >> 16);
}

// ---------------- pad copy: x[96x96] -> xp[98x98] interior ------------------
__global__ __launch_bounds__(256) void pad_copy(
    const float* __restrict__ in, float* __restrict__ outp)
{
  const int plane = blockIdx.x;   // 0..127 (b*64+c)
  const float* src = in + (size_t)plane * 9216;
  float* dst = outp + (size_t)plane * PLANE;
  for (int idx = threadIdx.x; idx < 9216; idx += 256) {
    const int y = idx / 96, x = idx - y * 96;
    dst[(y + 1) * PW + x + 1] = src[idx];
  }
}

// ---------------- conv3x3 + BN + ReLU, padded input, 8 co / block -----------
// Weights read with block-uniform indices -> scalar s_loads (no LDS, no VMEM).
template <bool PADOUT>
__global__ __launch_bounds__(256) void conv3x3_bn_relu(
    const float* __restrict__ in, const float* __restrict__ w,
    const float* __restrict__ gg, const float* __restrict__ bb_,
    const float* __restrict__ mm, const float* __restrict__ vv,
    float* __restrict__ out)
{
  __shared__ float inl[8][18][18];    // 8 ci planes, 16x16 tile + halo
  const int tile = blockIdx.x;        // 0..35
  const int cg   = blockIdx.y;        // 0..7
  const int b    = blockIdx.z;
  const int tx0 = (tile % 6) * 16, ty0 = (tile / 6) * 16;
  const int tid = threadIdx.x;
  const int tx = tid & 15, ty = tid >> 4;

  const float* inb = in + (size_t)b * 64 * PLANE;
  float acc[8];
#pragma unroll
  for (int c = 0; c < 8; ++c) acc[c] = 0.f;

  for (int c0 = 0; c0 < 64; c0 += 8) {
    __syncthreads();
    for (int idx = tid; idx < 2592; idx += 256) {
      const int cc = idx / 324, rem = idx - cc * 324;
      const int r = rem / 18, cx = rem - r * 18;
      inl[cc][r][cx] = inb[(size_t)(c0 + cc) * PLANE + (ty0 + r) * PW + tx0 + cx];
    }
    __syncthreads();
#pragma unroll
    for (int cc = 0; cc < 8; ++cc) {
      float r9[9];
#pragma unroll
      for (int kh = 0; kh < 3; ++kh)
#pragma unroll
        for (int kw = 0; kw < 3; ++kw) r9[kh * 3 + kw] = inl[cc][ty + kh][tx + kw];
#pragma unroll
      for (int c = 0; c < 8; ++c) {
        const float* wp = w + ((size_t)(cg * 8 + c) * 64 + c0 + cc) * 9;  // uniform
#pragma unroll
        for (int t = 0; t < 9; ++t) acc[c] += r9[t] * wp[t];
      }
    }
  }
#pragma unroll
  for (int c = 0; c < 8; ++c) {
    const int co = cg * 8 + c;
    const float sc = gg[co] * rsqrtf(vv[co] + 1e-5f);
    const float sh = bb_[co] - mm[co] * sc;
    const float val = fmaxf(sc * acc[c] + sh, 0.f);
    if (PADOUT)
      out[(size_t)(b * 64 + co) * PLANE + (ty0 + ty + 1) * PW + tx0 + tx + 1] = val;
    else
      out[((size_t)(b * 64 + co) * 96 + ty0 + ty) * 96 + tx0 + tx] = val;
  }
}

// ---------------- 1x1 q/k/v as bf16 MFMA GEMM -------------------------------
// cot 0 = q (x LOG2E) -> qtp[N][16]; 1 = k -> ktp[N][16];
// 2..5 = v channel-quarters -> vfrag fragment-linear layout:
//   element (c, pix): h=c>>5, l=(c&31)+32*((pix>>3)&1), jt=pix>>5,
//   ks=(pix>>4)&1, kk=pix&7 -> ushort idx (((jt*2+h)*2+ks)*64+l)*8+kk
__global__ __launch_bounds__(64) void qkv_kernel(
    const float* __restrict__ x1p,
    const float* __restrict__ wq, const float* __restrict__ bq,
    const float* __restrict__ wk, const float* __restrict__ bk,
    const float* __restrict__ wv, const float* __restrict__ bv,
    __hip_bfloat16* __restrict__ qtp, __hip_bfloat16* __restrict__ ktp,
    __hip_bfloat16* __restrict__ vfrag)
{
  const int pix0 = blockIdx.x * 16;
  const int cot  = blockIdx.y;
  const int b    = blockIdx.z;
  const int lane = threadIdx.x;
  const int g    = lane >> 4;
  const int col  = lane & 15;

  const float* wr;
  const float* bias;
  if (cot == 0)      { wr = wq + col * 64; bias = bq; }
  else if (cot == 1) { wr = wk + col * 64; bias = bk; }
  else               { wr = wv + ((cot - 2) * 16 + col) * 64; bias = bv + (cot - 2) * 16; }

  const int yy = pix0 / 96, xx = pix0 - yy * 96;
  const int ro = (yy + 1) * PW + xx + 1;

  f32x4 acc = (f32x4){0.f, 0.f, 0.f, 0.f};
  const float* xb = x1p + (size_t)b * 64 * PLANE;
#pragma unroll
  for (int kt = 0; kt < 2; ++kt) {
    const float4 wa = *(const float4*)(wr + kt * 32 + 8 * g);
    const float4 wb2 = *(const float4*)(wr + kt * 32 + 8 * g + 4);
    short8 af;
    af[0] = (short)f2bf(wa.x); af[1] = (short)f2bf(wa.y);
    af[2] = (short)f2bf(wa.z); af[3] = (short)f2bf(wa.w);
    af[4] = (short)f2bf(wb2.x); af[5] = (short)f2bf(wb2.y);
    af[6] = (short)f2bf(wb2.z); af[7] = (short)f2bf(wb2.w);
    short8 bf;
#pragma unroll
    for (int jj = 0; jj < 8; ++jj)
      bf[jj] = (short)f2bf(xb[(size_t)(kt * 32 + 8 * g + jj) * PLANE + ro + col]);
    acc = __builtin_amdgcn_mfma_f32_16x16x32_bf16(af, bf, acc, 0, 0, 0);
  }
  if (cot < 2) {
    unsigned short* dst = (unsigned short*)(cot == 0 ? qtp : ktp);
    dst += ((size_t)(b * NPIX + pix0 + col)) * 16;
    const float scl = (cot == 0) ? LOG2E : 1.f;
#pragma unroll
    for (int r = 0; r < 4; ++r) {
      const int cl = 4 * g + r;
      dst[cl] = f2bf((acc[r] + bias[cl]) * scl);
    }
  } else {
    unsigned short* dst = (unsigned short*)vfrag + (size_t)b * 589824;
    const int pix = pix0 + col;
    const int jt = pix >> 5, ks = (pix >> 4) & 1;
    const int lhalf = 32 * ((pix >> 3) & 1);
    const int kk = pix & 7;
#pragma unroll
    for (int r = 0; r < 4; ++r) {
      const int cl = 4 * g + r;
      const int c = (cot - 2) * 16 + cl;
      const int h = c >> 5;
      const int lA = (c & 31) + lhalf;
      dst[(size_t)((((jt * 2 + h) * 2 + ks) * 64 + lA)) * 8 + kk] =
          f2bf(acc[r] + bias[cl]);
    }
  }
}

// ---------------- flash attention, 32x32x16, in-register softmax ------------
// grid (288, 2), block 512 (8 waves). Wave w: j in [w*1152, (w+1)*1152).
__global__ __launch_bounds__(512, 4) void attn_kernel(
    const __hip_bfloat16* __restrict__ qtp, const __hip_bfloat16* __restrict__ ktp,
    const __hip_bfloat16* __restrict__ vfrag, const float* __restrict__ x1p,
    const float* __restrict__ gamma_p, float* __restrict__ ofp)
{
  __shared__ float2 mlb[8][32];
  __shared__ float obuf[32][65];
  __shared__ float lbuf[32];

  const int b   = blockIdx.y;
  const int i0  = blockIdx.x * 32;
  const int tid = threadIdx.x;
  const int w   = tid >> 6;
  const int lane = tid & 63;
  const int li  = lane & 31;
  const int hi  = lane >> 5;

  for (int idx = tid; idx < 32 * 65; idx += 512) ((float*)obuf)[idx] = 0.f;
  if (tid < 32) lbuf[tid] = 0.f;
  __syncthreads();

  const ushort* kb    = (const ushort*)ktp + (size_t)b * NPIX * 16;
  const ushort* vbase = (const ushort*)vfrag + (size_t)b * 589824;

  const short8 qf = *(const short8*)((const ushort*)qtp +
      ((size_t)b * NPIX + i0 + li) * 16 + 8 * hi);

  float m = -INFINITY, lsum = 0.f;
  f32x16 acc0 = {}, acc1 = {};

  const int jt0 = w * 36;
  // K frag addr: contiguous 1KB tile, lane-permuted within
  const ushort* kptr = kb + (size_t)(jt0 * 32 + li) * 16 + 8 * hi;
  // V frags: fragment-linear, lane-linear 1KB per (h,ks)
  const ushort* vptr = vbase + ((size_t)(jt0 * 4) * 64 + lane) * 8;

  short8 kf   = *(const short8*)kptr;
  short8 vf00 = *(const short8*)(vptr);            // h=0 ks=0
  short8 vf01 = *(const short8*)(vptr + 512);      // h=0 ks=1
  short8 vf10 = *(const short8*)(vptr + 1024);     // h=1 ks=0
  short8 vf11 = *(const short8*)(vptr + 1536);     // h=1 ks=1

  const f32x16 zf = {};
  for (int t = 0; t < 36; ++t) {
    f32x16 s = __builtin_amdgcn_mfma_f32_32x32x16_bf16(kf, qf, zf, 0, 0, 0);

    short8 kf_n, v00n, v01n, v10n, v11n;
    if (t < 35) {
      kptr += 512; vptr += 2048;
      kf_n = *(const short8*)kptr;
      v00n = *(const short8*)(vptr);
      v01n = *(const short8*)(vptr + 512);
      v10n = *(const short8*)(vptr + 1024);
      v11n = *(const short8*)(vptr + 1536);
    }

    // row max over tile: 16 regs + partner half via permlane32_swap
    float pm = fmaxf(fmaxf(fmaxf(s[0], s[1]), fmaxf(s[2], s[3])),
                     fmaxf(fmaxf(s[4], s[5]), fmaxf(s[6], s[7])));
    pm = fmaxf(pm, fmaxf(fmaxf(fmaxf(s[8], s[9]), fmaxf(s[10], s[11])),
                         fmaxf(fmaxf(s[12], s[13]), fmaxf(s[14], s[15]))));
    {
      float o = pm;
      asm("v_permlane32_swap_b32 %0, %1" : "+v"(o), "+v"(pm));
      pm = fmaxf(pm, o);
    }

    if (__any(pm > m + 8.f)) {    // defer-max rescale (T13)
      const float mnew = fmaxf(m, pm);
      const float corr = __builtin_amdgcn_exp2f(m - mnew);
      lsum *= corr;
      acc0 *= corr; acc1 *= corr;
      m = mnew;
    }

#pragma unroll
    for (int r = 0; r < 16; ++r) s[r] = __builtin_amdgcn_exp2f(s[r] - m);
    float ps = (((s[0] + s[1]) + (s[2] + s[3])) + ((s[4] + s[5]) + (s[6] + s[7]))) +
               (((s[8] + s[9]) + (s[10] + s[11])) + ((s[12] + s[13]) + (s[14] + s[15])));
    {
      float o = ps;
      asm("v_permlane32_swap_b32 %0, %1" : "+v"(o), "+v"(ps));
      ps = ps + o;
    }
    lsum += ps;

    // pack P to bf16 pairs, redistribute across hi halves (T12)
    u32 c01, c23, c45, c67, d01, d23, d45, d67;
    asm("v_cvt_pk_bf16_f32 %0, %1, %2" : "=v"(c01) : "v"(s[0]),  "v"(s[1]));
    asm("v_cvt_pk_bf16_f32 %0, %1, %2" : "=v"(c23) : "v"(s[2]),  "v"(s[3]));
    asm("v_cvt_pk_bf16_f32 %0, %1, %2" : "=v"(c45) : "v"(s[4]),  "v"(s[5]));
    asm("v_cvt_pk_bf16_f32 %0, %1, %2" : "=v"(c67) : "v"(s[6]),  "v"(s[7]));
    asm("v_cvt_pk_bf16_f32 %0, %1, %2" : "=v"(d01) : "v"(s[8]),  "v"(s[9]));
    asm("v_cvt_pk_bf16_f32 %0, %1, %2" : "=v"(d23) : "v"(s[10]), "v"(s[11]));
    asm("v_cvt_pk_bf16_f32 %0, %1, %2" : "=v"(d45) : "v"(s[12]), "v"(s[13]));
    asm("v_cvt_pk_bf16_f32 %0, %1, %2" : "=v"(d67) : "v"(s[14]), "v"(s[15]));
    asm("v_permlane32_swap_b32 %0, %1" : "+v"(c45), "+v"(c01));
    asm("v_permlane32_swap_b32 %0, %1" : "+v"(c67), "+v"(c23));
    asm("v_permlane32_swap_b32 %0, %1" : "+v"(d45), "+v"(d01));
    asm("v_permlane32_swap_b32 %0, %1" : "+v"(d67), "+v"(d23));
    const short8 pf1 = __builtin_bit_cast(short8, (u32x4){c01, c23, c45, c67});
    const short8 pf2 = __builtin_bit_cast(short8, (u32x4){d01, d23, d45, d67});

    acc0 = __builtin_amdgcn_mfma_f32_32x32x16_bf16(vf00, pf1, acc0, 0, 0, 0);
    acc0 = __builtin_amdgcn_mfma_f32_32x32x16_bf16(vf01, pf2, acc0, 0, 0, 0);
    acc1 = __builtin_amdgcn_mfma_f32_32x32x16_bf16(vf10, pf1, acc1, 0, 0, 0);
    acc1 = __builtin_amdgcn_mfma_f32_32x32x16_bf16(vf11, pf2, acc1, 0, 0, 0);

    if (t < 35) { kf = kf_n; vf00 = v00n; vf01 = v01n; vf10 = v10n; vf11 = v11n; }
  }

  // ---- merge 8 waves ----
  if (hi == 0) { float2 t2; t2.x = m; t2.y = lsum; mlb[w][li] = t2; }
  __syncthreads();
  float M = -INFINITY;
#pragma unroll
  for (int ww = 0; ww < 8; ++ww) M = fmaxf(M, mlb[ww][li].x);
  const float f = __builtin_amdgcn_exp2f(m - M);
  if (hi == 0) atomicAdd(&lbuf[li], lsum * f);
#pragma unroll
  for (int r = 0; r < 16; ++r) {
    const int c = (r & 3) + 8 * (r >> 2) + 4 * hi;
    atomicAdd(&obuf[li][c], acc0[r] * f);
    atomicAdd(&obuf[li][c + 32], acc1[r] * f);
  }
  __syncthreads();

  const float gm = gamma_p[0];
  const int yy = i0 / 96, xx = i0 - yy * 96;
  const int ro = (yy + 1) * PW + xx + 1;
  for (int idx = tid; idx < 2048; idx += 512) {
    const int il = idx & 31, c = idx >> 5;
    const size_t o = (size_t)(b * 64 + c) * PLANE + ro + il;
    ofp[o] = obuf[il][c] / lbuf[il] * gm + x1p[o];
  }
}

// ---------------------------------------------------------------------------
extern "C" void kernel_launch(void* const* d_in, const int* in_sizes, int n_in,
                              void* d_out, int out_size, void* d_ws, size_t ws_size,
                              hipStream_t stream) {
  const float* x      = (const float*)d_in[0];
  const float* w_pre  = (const float*)d_in[1];
  const float* bn1_g  = (const float*)d_in[2];
  const float* bn1_b  = (const float*)d_in[3];
  const float* bn1_m  = (const float*)d_in[4];
  const float* bn1_v  = (const float*)d_in[5];
  const float* wq     = (const float*)d_in[6];
  const float* bq     = (const float*)d_in[7];
  const float* wk     = (const float*)d_in[8];
  const float* bk     = (const float*)d_in[9];
  const float* wv     = (const float*)d_in[10];
  const float* bv     = (const float*)d_in[11];
  const float* w_fin  = (const float*)d_in[12];
  const float* bn2_g  = (const float*)d_in[13];
  const float* bn2_b  = (const float*)d_in[14];
  const float* bn2_m  = (const float*)d_in[15];
  const float* bn2_v  = (const float*)d_in[16];
  const float* gamma  = (const float*)d_in[17];
  float* out = (float*)d_out;

  char* ws = (char*)d_ws;
  float* xp  = (float*)(ws);                                   // 4,917,248 B (reused as ofp)
  float* x1p = (float*)(ws + 4917248);                         // 4,917,248 B
  __hip_bfloat16* qtp = (__hip_bfloat16*)(ws + 9834496);       //   589,824 B
  __hip_bfloat16* ktp = (__hip_bfloat16*)(ws + 10424320);      //   589,824 B
  __hip_bfloat16* vfr = (__hip_bfloat16*)(ws + 11014144);      // 2,359,296 B
  float* ofp = xp;   // xp dead after conv1; pad ring stays zero

  hipMemsetAsync(ws, 0, 9834496, stream);

  pad_copy<<<dim3(128), 256, 0, stream>>>(x, xp);
  conv3x3_bn_relu<true><<<dim3(36, 8, 2), 256, 0, stream>>>(
      xp, w_pre, bn1_g, bn1_b, bn1_m, bn1_v, x1p);
  qkv_kernel<<<dim3(576, 6, 2), 64, 0, stream>>>(
      x1p, wq, bq, wk, bk, wv, bv, qtp, ktp, vfr);
  attn_kernel<<<dim3(288, 2), 512, 0, stream>>>(
      qtp, ktp, vfr, x1p, gamma, ofp);
  conv3x3_bn_relu<false><<<dim3(36, 8, 2), 256, 0, stream>>>(
      ofp, w_fin, bn2_g, bn2_b, bn2_m, bn2_v, out);
}

// Round 6
// 182.099 us; speedup vs baseline: 3.6852x; 1.8434x over previous
//
#include <hip/hip_runtime.h>
#include <hip/hip_bf16.h>

// ---------------------------------------------------------------------------
// AttentionLayer round 5:
//  - round-4 architecture (MFMA convs, frag-linear V, QBLK=64 attn) with
//    precision hardening:
//    * q/k stored as split bf16 (hi+lo); energies via 3 MFMA -> 2^-17 accuracy
//    * conv split-bf16 uses all 4 products (xh*wh + xh*wl + xl*wh + xl*wl)
// ---------------------------------------------------------------------------

using short8 = __attribute__((ext_vector_type(8))) short;   // 8 bf16
using f32x4  = __attribute__((ext_vector_type(4))) float;
using f32x16 = __attribute__((ext_vector_type(16))) float;
using u32x4  = __attribute__((ext_vector_type(4))) unsigned;
typedef unsigned u32;
typedef unsigned short ushort;

#define NPIX 9216
#define PW 98
#define PLANE 9604            // fp32 padded plane (98*98)
#define PLANEB 9608           // bf16 padded plane, padded to 8 for b128 align
#define SEG 240               // staged window: 8+32+197, rounded to 8
#define LOG2E 1.44269504088896340736f

__device__ __forceinline__ ushort f2bf(float f) {
  u32 x = __builtin_bit_cast(u32, f);
  return (ushort)((x + 0x7fffu + ((x >> 16) & 1u)) >> 16);
}
__device__ __forceinline__ float bf2f(ushort h) {
  return __builtin_bit_cast(float, (u32)h << 16);
}

// ---------------- weight prep: OIHW fp32 -> frag-linear bf16 hi/lo ----------
__global__ __launch_bounds__(256) void wprep(
    const float* __restrict__ w_pre, const float* __restrict__ w_fin,
    ushort* __restrict__ fpre, ushort* __restrict__ ffin)
{
  const int i = blockIdx.x * 256 + threadIdx.x;    // [0, 36864)
  const float* w = blockIdx.y ? w_fin : w_pre;
  ushort* dst    = blockIdx.y ? ffin : fpre;
  const int kk = i & 7, l = (i >> 3) & 63, cot = (i >> 9) & 1;
  const int chunk = (i >> 10) & 3, tap = i >> 12;
  const int co = cot * 32 + (l & 31);
  const int ci = chunk * 16 + 8 * (l >> 5) + kk;
  const float wv = w[co * 576 + ci * 9 + tap];
  const ushort h = f2bf(wv);
  const ushort lo = f2bf(wv - bf2f(h));
  const int base = tap * 8192 + chunk * 2048 + cot * 1024 + l * 8 + kk;
  dst[base] = h;
  dst[base + 512] = lo;
}

// ---------------- pad+split: x fp32 [96x96] -> xh/xl bf16 [98x98] interior --
__global__ __launch_bounds__(256) void pad_split(
    const float* __restrict__ in, ushort* __restrict__ xh, ushort* __restrict__ xl)
{
  const int plane = blockIdx.x;   // 0..127
  const float* src = in + (size_t)plane * 9216;
  const size_t dbase = (size_t)plane * PLANEB;
  for (int idx = threadIdx.x; idx < 9216; idx += 256) {
    const int y = idx / 96, x = idx - y * 96;
    const float v = src[idx];
    const ushort h = f2bf(v);
    const size_t d = dbase + (y + 1) * PW + x + 1;
    xh[d] = h;
    xl[d] = f2bf(v - bf2f(h));
  }
}

// ---------------- conv3x3 + BN + ReLU via MFMA (split-bf16, 4 products) -----
template <bool PADOUT>
__global__ __launch_bounds__(128) void conv3x3_mfma(
    const ushort* __restrict__ xh, const ushort* __restrict__ xl,
    const ushort* __restrict__ wfrag,
    const float* __restrict__ gg, const float* __restrict__ bb_,
    const float* __restrict__ mm, const float* __restrict__ vv,
    float* __restrict__ outp)
{
  __shared__ ushort stage[2][SEG][18];   // [hl][e][ci], 36B rows (bank-clean)
  __shared__ float scb[64], shb[64];
  const int n0  = blockIdx.x * 32;
  const int b   = blockIdx.y;
  const int tid = threadIdx.x;
  const int wm  = tid >> 6;
  const int lane = tid & 63;
  const int li = lane & 31, hi = lane >> 5;

  if (tid < 64) {
    const float sc = gg[tid] * rsqrtf(vv[tid] + 1e-5f);
    scb[tid] = sc;
    shb[tid] = bb_[tid] - mm[tid] * sc;
  }

  f32x16 acc = {};
  const int sbase = n0 - 8;

  for (int chunk = 0; chunk < 4; ++chunk) {
    __syncthreads();
#pragma unroll
    for (int it = 0; it < 8; ++it) {
      const int item = tid + it * 128;
      if (item < 960) {
        const int pl   = item >= 480;
        const int rem  = pl ? item - 480 : item;
        const int eblk = rem >> 4;
        const int ci   = rem & 15;
        const ushort* src = (pl ? xl : xh) +
            (size_t)(b * 64 + chunk * 16 + ci) * PLANEB + sbase + eblk * 8;
        const short8 v = *(const short8*)src;
#pragma unroll
        for (int j = 0; j < 8; ++j) stage[pl][eblk * 8 + j][ci] = (ushort)v[j];
      }
    }
    __syncthreads();

    const ushort* wb0 = wfrag + (size_t)(chunk * 2048 + wm * 1024 + lane * 8);
    short8 ah = *(const short8*)(wb0);
    short8 al = *(const short8*)(wb0 + 512);
#pragma unroll
    for (int tap = 0; tap < 9; ++tap) {
      const int eoff = (tap / 3) * PW + (tap % 3) + 7 + li;
      const short8 bh = *(const short8*)&stage[0][eoff][hi * 8];
      const short8 bl = *(const short8*)&stage[1][eoff][hi * 8];
      short8 ahn, aln;
      if (tap < 8) {
        const ushort* wbn = wb0 + (size_t)(tap + 1) * 8192;
        ahn = *(const short8*)(wbn);
        aln = *(const short8*)(wbn + 512);
      }
      acc = __builtin_amdgcn_mfma_f32_32x32x16_bf16(ah, bh, acc, 0, 0, 0);
      acc = __builtin_amdgcn_mfma_f32_32x32x16_bf16(ah, bl, acc, 0, 0, 0);
      acc = __builtin_amdgcn_mfma_f32_32x32x16_bf16(al, bh, acc, 0, 0, 0);
      acc = __builtin_amdgcn_mfma_f32_32x32x16_bf16(al, bl, acc, 0, 0, 0);
      if (tap < 8) { ah = ahn; al = aln; }
    }
  }

  const int pix = n0 + li;
  const int y = pix / PW;
  const int x = pix - y * PW;
  if (x >= 1 && x <= 96) {
#pragma unroll
    for (int r = 0; r < 16; ++r) {
      const int co = wm * 32 + (r & 3) + 8 * (r >> 2) + 4 * hi;
      const float val = fmaxf(scb[co] * acc[r] + shb[co], 0.f);
      if (PADOUT)
        outp[(size_t)(b * 64 + co) * PLANE + pix + PW] = val;
      else
        outp[(size_t)(b * 64 + co) * 9216 + y * 96 + (x - 1)] = val;
    }
  }
}

// ---------------- 1x1 q/k/v as bf16 MFMA GEMM -------------------------------
// cot 0 = q (x LOG2E) -> qsp[N][32] (hi 0..15, lo 16..31); 1 = k -> ksp same;
// 2..5 = v channel-quarters -> vfrag fragment-linear.
__global__ __launch_bounds__(64) void qkv_kernel(
    const float* __restrict__ x1p,
    const float* __restrict__ wq, const float* __restrict__ bq,
    const float* __restrict__ wk, const float* __restrict__ bk,
    const float* __restrict__ wv, const float* __restrict__ bv,
    ushort* __restrict__ qsp, ushort* __restrict__ ksp,
    ushort* __restrict__ vfrag)
{
  const int pix0 = blockIdx.x * 16;
  const int cot  = blockIdx.y;
  const int b    = blockIdx.z;
  const int lane = threadIdx.x;
  const int g    = lane >> 4;
  const int col  = lane & 15;

  const float* wr;
  const float* bias;
  if (cot == 0)      { wr = wq + col * 64; bias = bq; }
  else if (cot == 1) { wr = wk + col * 64; bias = bk; }
  else               { wr = wv + ((cot - 2) * 16 + col) * 64; bias = bv + (cot - 2) * 16; }

  const int yy = pix0 / 96, xx = pix0 - yy * 96;
  const int ro = (yy + 1) * PW + xx + 1;

  f32x4 acc = (f32x4){0.f, 0.f, 0.f, 0.f};
  const float* xb = x1p + (size_t)b * 64 * PLANE;
#pragma unroll
  for (int kt = 0; kt < 2; ++kt) {
    const float4 wa = *(const float4*)(wr + kt * 32 + 8 * g);
    const float4 wb2 = *(const float4*)(wr + kt * 32 + 8 * g + 4);
    short8 af;
    af[0] = (short)f2bf(wa.x); af[1] = (short)f2bf(wa.y);
    af[2] = (short)f2bf(wa.z); af[3] = (short)f2bf(wa.w);
    af[4] = (short)f2bf(wb2.x); af[5] = (short)f2bf(wb2.y);
    af[6] = (short)f2bf(wb2.z); af[7] = (short)f2bf(wb2.w);
    short8 bf;
#pragma unroll
    for (int jj = 0; jj < 8; ++jj)
      bf[jj] = (short)f2bf(xb[(size_t)(kt * 32 + 8 * g + jj) * PLANE + ro + col]);
    acc = __builtin_amdgcn_mfma_f32_16x16x32_bf16(af, bf, acc, 0, 0, 0);
  }
  if (cot < 2) {
    ushort* dst = (cot == 0 ? qsp : ksp) + ((size_t)(b * NPIX + pix0 + col)) * 32;
    const float scl = (cot == 0) ? LOG2E : 1.f;
#pragma unroll
    for (int r = 0; r < 4; ++r) {
      const int cl = 4 * g + r;
      const float val = (acc[r] + bias[cl]) * scl;
      const ushort h = f2bf(val);
      dst[cl] = h;
      dst[16 + cl] = f2bf(val - bf2f(h));
    }
  } else {
    ushort* dst = vfrag + (size_t)b * 589824;
    const int pix = pix0 + col;
    const int jt = pix >> 5, ks = (pix >> 4) & 1;
    const int lhalf = 32 * ((pix >> 3) & 1);
    const int kk = pix & 7;
#pragma unroll
    for (int r = 0; r < 4; ++r) {
      const int cl = 4 * g + r;
      const int c = (cot - 2) * 16 + cl;
      const int h = c >> 5;
      const int lA = (c & 31) + lhalf;
      dst[(size_t)((((jt * 2 + h) * 2 + ks) * 64 + lA)) * 8 + kk] =
          f2bf(acc[r] + bias[cl]);
    }
  }
}

// ---------------- flash attention, QBLK=64, 4-wave j-split, split-QK --------
// grid (144, 2), block 256. Wave w: j in [w*2304, (w+1)*2304), 72 tiles of 32.
__global__ __launch_bounds__(256, 3) void attn_kernel(
    const ushort* __restrict__ qsp, const ushort* __restrict__ ksp,
    const ushort* __restrict__ vfrag, const float* __restrict__ x1p,
    const float* __restrict__ gamma_p,
    ushort* __restrict__ ofh, ushort* __restrict__ ofl)
{
  __shared__ float2 mlb[4][64];
  __shared__ float obuf[64][65];
  __shared__ float lbuf[64];

  const int b   = blockIdx.y;
  const int i0  = blockIdx.x * 64;
  const int tid = threadIdx.x;
  const int w   = tid >> 6;
  const int lane = tid & 63;
  const int li  = lane & 31;
  const int hi  = lane >> 5;

  for (int idx = tid; idx < 64 * 65; idx += 256) ((float*)obuf)[idx] = 0.f;
  if (tid < 64) lbuf[tid] = 0.f;
  __syncthreads();

  const ushort* kb    = ksp + (size_t)b * NPIX * 32;
  const ushort* vbase = vfrag + (size_t)b * 589824;

  short8 qfh[2], qfl[2];
#pragma unroll
  for (int qh = 0; qh < 2; ++qh) {
    const ushort* qrow = qsp + ((size_t)b * NPIX + i0 + qh * 32 + li) * 32 + 8 * hi;
    qfh[qh] = *(const short8*)(qrow);
    qfl[qh] = *(const short8*)(qrow + 16);
  }

  float m[2] = {-INFINITY, -INFINITY};
  float lsum[2] = {0.f, 0.f};
  f32x16 acc[2][2] = {};

  const int jt0 = w * 72;
  const ushort* kptr = kb + (size_t)(jt0 * 32 + li) * 32 + 8 * hi;
  const ushort* vptr = vbase + ((size_t)(jt0 * 4) * 64 + lane) * 8;

  short8 kfh  = *(const short8*)kptr;
  short8 kfl  = *(const short8*)(kptr + 16);
  short8 vf00 = *(const short8*)(vptr);
  short8 vf01 = *(const short8*)(vptr + 512);
  short8 vf10 = *(const short8*)(vptr + 1024);
  short8 vf11 = *(const short8*)(vptr + 1536);

  const f32x16 zf = {};
  for (int t = 0; t < 72; ++t) {
    f32x16 sv[2];
#pragma unroll
    for (int qh = 0; qh < 2; ++qh) {
      sv[qh] = __builtin_amdgcn_mfma_f32_32x32x16_bf16(kfh, qfh[qh], zf, 0, 0, 0);
      sv[qh] = __builtin_amdgcn_mfma_f32_32x32x16_bf16(kfl, qfh[qh], sv[qh], 0, 0, 0);
      sv[qh] = __builtin_amdgcn_mfma_f32_32x32x16_bf16(kfh, qfl[qh], sv[qh], 0, 0, 0);
    }

    short8 kfh_n, kfl_n, v00n, v01n, v10n, v11n;
    if (t < 71) {
      kptr += 1024; vptr += 2048;
      kfh_n = *(const short8*)kptr;
      kfl_n = *(const short8*)(kptr + 16);
      v00n = *(const short8*)(vptr);
      v01n = *(const short8*)(vptr + 512);
      v10n = *(const short8*)(vptr + 1024);
      v11n = *(const short8*)(vptr + 1536);
    }

#pragma unroll
    for (int qh = 0; qh < 2; ++qh) {
      f32x16 s = sv[qh];
      float pm = fmaxf(fmaxf(fmaxf(s[0], s[1]), fmaxf(s[2], s[3])),
                       fmaxf(fmaxf(s[4], s[5]), fmaxf(s[6], s[7])));
      pm = fmaxf(pm, fmaxf(fmaxf(fmaxf(s[8], s[9]), fmaxf(s[10], s[11])),
                           fmaxf(fmaxf(s[12], s[13]), fmaxf(s[14], s[15]))));
      {
        float o = pm;
        asm("v_permlane32_swap_b32 %0, %1" : "+v"(o), "+v"(pm));
        pm = fmaxf(pm, o);
      }

      if (__any(pm > m[qh] + 8.f)) {   // defer-max rescale (T13)
        const float mnew = fmaxf(m[qh], pm);
        const float corr = __builtin_amdgcn_exp2f(m[qh] - mnew);
        lsum[qh] *= corr;
        acc[qh][0] *= corr;
        acc[qh][1] *= corr;
        m[qh] = mnew;
      }

#pragma unroll
      for (int r = 0; r < 16; ++r) s[r] = __builtin_amdgcn_exp2f(s[r] - m[qh]);
      float ps = (((s[0] + s[1]) + (s[2] + s[3])) + ((s[4] + s[5]) + (s[6] + s[7]))) +
                 (((s[8] + s[9]) + (s[10] + s[11])) + ((s[12] + s[13]) + (s[14] + s[15])));
      {
        float o = ps;
        asm("v_permlane32_swap_b32 %0, %1" : "+v"(o), "+v"(ps));
        ps = ps + o;
      }
      lsum[qh] += ps;

      u32 c01, c23, c45, c67, d01, d23, d45, d67;
      asm("v_cvt_pk_bf16_f32 %0, %1, %2" : "=v"(c01) : "v"(s[0]),  "v"(s[1]));
      asm("v_cvt_pk_bf16_f32 %0, %1, %2" : "=v"(c23) : "v"(s[2]),  "v"(s[3]));
      asm("v_cvt_pk_bf16_f32 %0, %1, %2" : "=v"(c45) : "v"(s[4]),  "v"(s[5]));
      asm("v_cvt_pk_bf16_f32 %0, %1, %2" : "=v"(c67) : "v"(s[6]),  "v"(s[7]));
      asm("v_cvt_pk_bf16_f32 %0, %1, %2" : "=v"(d01) : "v"(s[8]),  "v"(s[9]));
      asm("v_cvt_pk_bf16_f32 %0, %1, %2" : "=v"(d23) : "v"(s[10]), "v"(s[11]));
      asm("v_cvt_pk_bf16_f32 %0, %1, %2" : "=v"(d45) : "v"(s[12]), "v"(s[13]));
      asm("v_cvt_pk_bf16_f32 %0, %1, %2" : "=v"(d67) : "v"(s[14]), "v"(s[15]));
      asm("v_permlane32_swap_b32 %0, %1" : "+v"(c45), "+v"(c01));
      asm("v_permlane32_swap_b32 %0, %1" : "+v"(c67), "+v"(c23));
      asm("v_permlane32_swap_b32 %0, %1" : "+v"(d45), "+v"(d01));
      asm("v_permlane32_swap_b32 %0, %1" : "+v"(d67), "+v"(d23));
      const short8 pf1 = __builtin_bit_cast(short8, (u32x4){c01, c23, c45, c67});
      const short8 pf2 = __builtin_bit_cast(short8, (u32x4){d01, d23, d45, d67});

      acc[qh][0] = __builtin_amdgcn_mfma_f32_32x32x16_bf16(vf00, pf1, acc[qh][0], 0, 0, 0);
      acc[qh][0] = __builtin_amdgcn_mfma_f32_32x32x16_bf16(vf01, pf2, acc[qh][0], 0, 0, 0);
      acc[qh][1] = __builtin_amdgcn_mfma_f32_32x32x16_bf16(vf10, pf1, acc[qh][1], 0, 0, 0);
      acc[qh][1] = __builtin_amdgcn_mfma_f32_32x32x16_bf16(vf11, pf2, acc[qh][1], 0, 0, 0);
    }

    if (t < 71) {
      kfh = kfh_n; kfl = kfl_n;
      vf00 = v00n; vf01 = v01n; vf10 = v10n; vf11 = v11n;
    }
  }

  // ---- merge 4 waves ----
  if (hi == 0) {
#pragma unroll
    for (int qh = 0; qh < 2; ++qh) {
      float2 t2; t2.x = m[qh]; t2.y = lsum[qh];
      mlb[w][qh * 32 + li] = t2;
    }
  }
  __syncthreads();
  float f[2];
#pragma unroll
  for (int qh = 0; qh < 2; ++qh) {
    float M = -INFINITY;
#pragma unroll
    for (int ww = 0; ww < 4; ++ww) M = fmaxf(M, mlb[ww][qh * 32 + li].x);
    f[qh] = __builtin_amdgcn_exp2f(m[qh] - M);
  }
  if (hi == 0) {
#pragma unroll
    for (int qh = 0; qh < 2; ++qh) atomicAdd(&lbuf[qh * 32 + li], lsum[qh] * f[qh]);
  }
#pragma unroll
  for (int qh = 0; qh < 2; ++qh)
#pragma unroll
    for (int hh = 0; hh < 2; ++hh)
#pragma unroll
      for (int r = 0; r < 16; ++r) {
        const int c = (r & 3) + 8 * (r >> 2) + 4 * hi + 32 * hh;
        atomicAdd(&obuf[qh * 32 + li][c], acc[qh][hh][r] * f[qh]);
      }
  __syncthreads();

  const float gm = gamma_p[0];
  for (int idx = tid; idx < 4096; idx += 256) {
    const int il = idx & 63, c = idx >> 6;
    const int p = i0 + il;
    const int y = p / 96, x = p - y * 96;
    const int ro = (y + 1) * PW + x + 1;
    const float val = obuf[il][c] / lbuf[il] * gm +
                      x1p[(size_t)(b * 64 + c) * PLANE + ro];
    const ushort h = f2bf(val);
    const size_t d = (size_t)(b * 64 + c) * PLANEB + ro;
    ofh[d] = h;
    ofl[d] = f2bf(val - bf2f(h));
  }
}

// ---------------------------------------------------------------------------
extern "C" void kernel_launch(void* const* d_in, const int* in_sizes, int n_in,
                              void* d_out, int out_size, void* d_ws, size_t ws_size,
                              hipStream_t stream) {
  const float* x      = (const float*)d_in[0];
  const float* w_pre  = (const float*)d_in[1];
  const float* bn1_g  = (const float*)d_in[2];
  const float* bn1_b  = (const float*)d_in[3];
  const float* bn1_m  = (const float*)d_in[4];
  const float* bn1_v  = (const float*)d_in[5];
  const float* wq     = (const float*)d_in[6];
  const float* bq     = (const float*)d_in[7];
  const float* wk     = (const float*)d_in[8];
  const float* bk     = (const float*)d_in[9];
  const float* wv     = (const float*)d_in[10];
  const float* bv     = (const float*)d_in[11];
  const float* w_fin  = (const float*)d_in[12];
  const float* bn2_g  = (const float*)d_in[13];
  const float* bn2_b  = (const float*)d_in[14];
  const float* bn2_m  = (const float*)d_in[15];
  const float* bn2_v  = (const float*)d_in[16];
  const float* gamma  = (const float*)d_in[17];
  float* out = (float*)d_out;

  char* ws = (char*)d_ws;
  float*  x1p  = (float*)(ws);                       // 4,917,248 B
  ushort* xh   = (ushort*)(ws + 4917248);            // 2,459,648 B
  ushort* xl   = (ushort*)(ws + 7376896);            // 2,459,648 B
  ushort* qsp  = (ushort*)(ws + 9836544);            // 1,179,648 B
  ushort* ksp  = (ushort*)(ws + 11016192);           // 1,179,648 B
  ushort* vfr  = (ushort*)(ws + 12195840);           // 2,359,296 B
  ushort* fpre = (ushort*)(ws + 14555136);           //   147,456 B
  ushort* ffin = (ushort*)(ws + 14702592);           //   147,456 B -> end 14,850,048
  ushort* ofh = xh;   // xh/xl dead after conv1; reuse for attn output planes
  ushort* ofl = xl;

  // zero bf16 plane region (pad rings must be 0; interiors rewritten each call)
  hipMemsetAsync(ws + 4917248, 0, 4919296, stream);

  wprep<<<dim3(144, 2), 256, 0, stream>>>(w_pre, w_fin, fpre, ffin);
  pad_split<<<dim3(128), 256, 0, stream>>>(x, xh, xl);
  conv3x3_mfma<true><<<dim3(294, 2), 128, 0, stream>>>(
      xh, xl, fpre, bn1_g, bn1_b, bn1_m, bn1_v, x1p);
  qkv_kernel<<<dim3(576, 6, 2), 64, 0, stream>>>(
      x1p, wq, bq, wk, bk, wv, bv, qsp, ksp, vfr);
  attn_kernel<<<dim3(144, 2), 256, 0, stream>>>(
      qsp, ksp, vfr, x1p, gamma, ofh, ofl);
  conv3x3_mfma<false><<<dim3(294, 2), 128, 0, stream>>>(
      ofh, ofl, ffin, bn2_g, bn2_b, bn2_m, bn2_v, out);
}